// Round 8
// baseline (895.354 us; speedup 1.0000x reference)
//
#include <hip/hip_runtime.h>

// WaveNet on gfx950, fp16 MFMA path, round 13.
// r10 (64-tiles) 849us and r12 (128-tiles) 834us both sit at ~38us per
// phase-step == r5's per-dispatch time, though the data critical path is only
// ~22 steps. Hypotheses: H1 = 2-slot ping-pong WAR forces +-1-phase lockstep,
// per-step cost = max of 64 jittery bodies; H2 = body itself ~30us serial.
// r13 tests H1, all else r12-proven:
//  (1) 3-slot rotation (phase q -> slab (q-1)%3): WAR slack 1 -> 2 phases.
//      nslots picked HOST-side from ws_size (>=70MB -> 3; else r12 2-slot).
//      R0g doubles as phase-0 publish (layer 1 taps R0g; input publish gone).
//  (2) register-direct publish + flag one barrier earlier (6 -> 5 barriers).
//  (3) g_broken poll thinned 16 -> 256 iters (shared-line LLC pressure).
// Protocol otherwise r12: XCD-affine light mode, sc0 staging loads, plain
// stores + vmcnt(0) release, LLC-resolved relaxed atomic flags, bounded
// spins + sticky g_broken, heavy fallback with agent fences.

#define TT 8192
#define HIDC 128
#define GOODC 2046
#define TGT 6146
#define NL 20
#define TILE 128
#define NTB 64
#define NTILES 512
#define NBLK 512
#define GATE_CAP (1 << 18)
#define RDV_CAP (1 << 16)

typedef _Float16 half8_t __attribute__((ext_vector_type(8)));
typedef _Float16 half4_t __attribute__((ext_vector_type(4)));
typedef float floatx4 __attribute__((ext_vector_type(4)));

__device__ int g_progress[NTILES];
__device__ int g_qhead[8];
__device__ int g_arrive;
__device__ int g_broken;

__device__ __forceinline__ floatx4 mfma16(half8_t a, half8_t b, floatx4 c) {
  return __builtin_amdgcn_mfma_f32_16x16x32_f16(a, b, c, 0, 0, 0);
}
__device__ __forceinline__ float fast_sigmoid(float x) {
  return __builtin_amdgcn_rcpf(1.0f + __expf(-x));
}
__device__ __forceinline__ float fast_tanh(float x) {
  return 2.0f * __builtin_amdgcn_rcpf(1.0f + __expf(-2.0f * x)) - 1.0f;
}

// 8 L1-bypass (sc0) 16B loads, one waitcnt (L2 is the light-mode coherence pt)
__device__ __forceinline__ void cload8(
    const void* p0, const void* p1, const void* p2, const void* p3,
    const void* p4, const void* p5, const void* p6, const void* p7,
    floatx4& r0, floatx4& r1, floatx4& r2, floatx4& r3,
    floatx4& r4, floatx4& r5, floatx4& r6, floatx4& r7) {
  asm volatile(
      "global_load_dwordx4 %0, %8, off sc0\n\t"
      "global_load_dwordx4 %1, %9, off sc0\n\t"
      "global_load_dwordx4 %2, %10, off sc0\n\t"
      "global_load_dwordx4 %3, %11, off sc0\n\t"
      "global_load_dwordx4 %4, %12, off sc0\n\t"
      "global_load_dwordx4 %5, %13, off sc0\n\t"
      "global_load_dwordx4 %6, %14, off sc0\n\t"
      "global_load_dwordx4 %7, %15, off sc0\n\t"
      "s_waitcnt vmcnt(0)"
      : "=&v"(r0), "=&v"(r1), "=&v"(r2), "=&v"(r3),
        "=&v"(r4), "=&v"(r5), "=&v"(r6), "=&v"(r7)
      : "v"(p0), "v"(p1), "v"(p2), "v"(p3),
        "v"(p4), "v"(p5), "v"(p6), "v"(p7)
      : "memory");
}
__device__ __forceinline__ void cload4(const void* p0, const void* p1,
                                       const void* p2, const void* p3,
                                       floatx4& r0, floatx4& r1, floatx4& r2,
                                       floatx4& r3) {
  asm volatile(
      "global_load_dwordx4 %0, %4, off sc0\n\t"
      "global_load_dwordx4 %1, %5, off sc0\n\t"
      "global_load_dwordx4 %2, %6, off sc0\n\t"
      "global_load_dwordx4 %3, %7, off sc0\n\t"
      "s_waitcnt vmcnt(0)"
      : "=&v"(r0), "=&v"(r1), "=&v"(r2), "=&v"(r3)
      : "v"(p0), "v"(p1), "v"(p2), "v"(p3)
      : "memory");
}

// r10/r12-proven bounded spin: LLC-resolved relaxed agent atomic load
__device__ __forceinline__ void spin_tile(int idx, int q) {
  int* f = &g_progress[idx];
  int it = 0;
  while (__hip_atomic_load(f, __ATOMIC_RELAXED, __HIP_MEMORY_SCOPE_AGENT) < q) {
    if (!(++it & 255) && __hip_atomic_load(&g_broken, __ATOMIC_RELAXED,
                                           __HIP_MEMORY_SCOPE_AGENT))
      break;
    if (it > GATE_CAP) {
      __hip_atomic_store(&g_broken, 1, __ATOMIC_RELAXED,
                         __HIP_MEMORY_SCOPE_AGENT);
      break;
    }
    __builtin_amdgcn_s_sleep(1);
  }
}

// ---------------- weight prep + flag reset ----------------
__global__ void prep_kernel(const float* __restrict__ Wi, const float* __restrict__ Wf,
                            const float* __restrict__ Wg, const float* __restrict__ Wr,
                            const float* __restrict__ W1, const float* __restrict__ W2,
                            _Float16* __restrict__ WIh, _Float16* __restrict__ WFG,
                            _Float16* __restrict__ WRh, _Float16* __restrict__ W1h,
                            _Float16* __restrict__ W2h) {
  int idx = blockIdx.x * blockDim.x + threadIdx.x;
  int stride = gridDim.x * blockDim.x;
  for (int i = idx; i < NTILES; i += stride) g_progress[i] = 0;
  for (int i = idx; i < 8; i += stride) g_qhead[i] = 0;
  if (idx == 0) { g_arrive = 0; g_broken = 0; }
  for (int i = idx; i < NL * 256 * 256; i += stride) {
    int l = i >> 16; int m = (i >> 8) & 255; int k = i & 255;
    int tap = k >> 7; int ci = k & 127;
    float v;
    if (m < 128) v = Wf[(((size_t)l * 128 + m) * 128 + ci) * 2 + tap];
    else         v = Wg[(((size_t)l * 128 + (m - 128)) * 128 + ci) * 2 + tap];
    WFG[i] = (_Float16)v;
  }
  for (int i = idx; i < NL * 128 * 128; i += stride) WRh[i] = (_Float16)Wr[i];
  for (int i = idx; i < 128 * 256; i += stride) WIh[i] = (_Float16)Wi[i];
  for (int i = idx; i < 512 * 128; i += stride) W1h[i] = (_Float16)W1[i];
  for (int i = idx; i < 256 * 512; i += stride) W2h[i] = (_Float16)W2[i];
}

// ---------------- phase 0 (one 64-row half): input conv ----------------
// Writes Rown (LDS) + R0g (global, full tile). R0g IS the phase-0 publish.
__device__ __forceinline__ void input_half(
    const float* __restrict__ ib, const _Float16* __restrict__ WIh,
    const float* __restrict__ bi, _Float16* __restrict__ R0g,
    int u0t, int h, char* smem) {
  _Float16(*Rown)[136] = (_Float16(*)[136])smem;
  _Float16(*Xs)[264] = (_Float16(*)[264])(smem + 34816);
  const int u0 = u0t + 64 * h;
  const int tid = threadIdx.x;
  const int lane = tid & 63;
  const int w = tid >> 6;
  const int ml = lane & 15;
  const int mq = lane >> 4;

#pragma unroll
  for (int it = 0; it < 4; ++it) {
    int i = it * 256 + tid;
    int n4 = i & 15;
    int kg = i >> 4;
    const float* src = ib + (size_t)(kg * 4) * TT + u0 + n4 * 4;
    floatx4 c0 = *(const floatx4*)(src);
    floatx4 c1 = *(const floatx4*)(src + TT);
    floatx4 c2 = *(const floatx4*)(src + 2 * TT);
    floatx4 c3 = *(const floatx4*)(src + 3 * TT);
#pragma unroll
    for (int tq = 0; tq < 4; ++tq) {
      half4_t hh;
      hh[0] = (_Float16)c0[tq]; hh[1] = (_Float16)c1[tq];
      hh[2] = (_Float16)c2[tq]; hh[3] = (_Float16)c3[tq];
      *(half4_t*)&Xs[n4 * 4 + tq][kg * 4] = hh;
    }
  }
  __syncthreads();

  floatx4 acc[2][4];
#pragma unroll
  for (int a = 0; a < 2; ++a)
#pragma unroll
    for (int c = 0; c < 4; ++c) acc[a][c] = floatx4{0.f, 0.f, 0.f, 0.f};
  const _Float16* Aw = WIh + (size_t)(32 * w + ml) * 256;
#pragma unroll
  for (int kk = 0; kk < 8; ++kk) {
    const int ko = kk * 32 + mq * 8;
    half8_t a0 = *(const half8_t*)(Aw + ko);
    half8_t a1 = *(const half8_t*)(Aw + 16 * 256 + ko);
#pragma unroll
    for (int nt = 0; nt < 4; ++nt) {
      half8_t bv = *(const half8_t*)&Xs[nt * 16 + ml][ko];
      acc[0][nt] = mfma16(a0, bv, acc[0][nt]);
      acc[1][nt] = mfma16(a1, bv, acc[1][nt]);
    }
  }
  __syncthreads();
  float* Xf = (float*)(smem + 34816);
#pragma unroll
  for (int mt = 0; mt < 2; ++mt) {
    const int mb = 32 * w + mt * 16 + mq * 4;
#pragma unroll
    for (int nt = 0; nt < 4; ++nt)
      *(floatx4*)&Xf[(nt * 16 + ml) * 132 + mb] = acc[mt][nt];
  }
  __syncthreads();
#pragma unroll
  for (int it = 0; it < 4; ++it) {
    int i = it * 256 + tid;
    int n = i >> 4; int cq = i & 15;
    floatx4 x0 = *(const floatx4*)&Xf[n * 132 + cq * 8];
    floatx4 x1 = *(const floatx4*)&Xf[n * 132 + cq * 8 + 4];
    floatx4 b0 = *(const floatx4*)(bi + cq * 8);
    floatx4 b1v = *(const floatx4*)(bi + cq * 8 + 4);
    half8_t hh;
#pragma unroll
    for (int tq = 0; tq < 4; ++tq) {
      hh[tq] = (_Float16)(x0[tq] + b0[tq]);
      hh[4 + tq] = (_Float16)(x1[tq] + b1v[tq]);
    }
    *(half8_t*)&Rown[64 * h + n][cq * 8] = hh;
    *(half8_t*)(R0g + (size_t)(u0 + n) * HIDC + cq * 8) = hh;
  }
  __syncthreads();  // Xf reads done; scratch reusable by next half
}

// ---------------- phases 1..20: one layer, 128-row tile in LDS --------------
// Publishes tail ext rows DIRECTLY FROM REGISTERS; caller drains + flags.
__device__ __forceinline__ void phase_layer(
    const _Float16* __restrict__ pbin, _Float16* __restrict__ pbout,
    const _Float16* __restrict__ WFGl, const _Float16* __restrict__ WRl,
    const float* __restrict__ bfl, const float* __restrict__ bgl,
    const float* __restrict__ brl, int d, int u0, int ext, char* smem) {
  _Float16(*Rown)[136] = (_Float16(*)[136])smem;            // persistent R
  _Float16(*Xs0)[136] = (_Float16(*)[136])(smem + 34816);   // tap0 prefix; Os
  const int tid = threadIdx.x;
  const int lane = tid & 63;
  const int w = tid >> 6;
  const int ml = lane & 15;
  const int mq = lane >> 4;

  // ---- stage tap0 prefix: dd = min(d,128) rows via sc0 loads ----
  const int dd = d < TILE ? d : TILE;
  const int nch = dd << 4;              // 16B chunks
  {
    const void* sp[8];
#pragma unroll
    for (int k = 0; k < 8; ++k) {
      int i = tid + (k << 8);
      int row = i >> 4, cc = i & 15;
      int p = u0 - d + row;
      if (p < 0) p = 0;                 // left-edge garbage never consumed
      sp[k] = (i < nch) ? (const void*)(pbin + (size_t)p * HIDC + cc * 8)
                        : (const void*)pbin;
    }
    floatx4 rr0, rr1, rr2, rr3, rr4, rr5, rr6, rr7;
    cload8(sp[0], sp[1], sp[2], sp[3], sp[4], sp[5], sp[6], sp[7],
           rr0, rr1, rr2, rr3, rr4, rr5, rr6, rr7);
    floatx4 rr[8] = {rr0, rr1, rr2, rr3, rr4, rr5, rr6, rr7};
#pragma unroll
    for (int k = 0; k < 8; ++k) {
      int i = tid + (k << 8);
      if (i < nch) *(floatx4*)&Xs0[i >> 4][(i & 15) * 8] = rr[k];
    }
  }
  __syncthreads();  // b1

  // ---- B-row pointers ----
  const _Float16* brow0[8];
  const _Float16* brow1[8];
#pragma unroll
  for (int nt = 0; nt < 8; ++nt) {
    int n = nt * 16 + ml;
    brow1[nt] = &Rown[n][0];
    brow0[nt] = (n < dd) ? &Xs0[n][0] : &Rown[n - d][0];
  }

  // ---- GEMM1: [f;g](256) x N=128 x K=256 ----
  floatx4 accF[2][8], accG[2][8];
#pragma unroll
  for (int a = 0; a < 2; ++a)
#pragma unroll
    for (int cc = 0; cc < 8; ++cc) {
      accF[a][cc] = floatx4{0.f, 0.f, 0.f, 0.f};
      accG[a][cc] = floatx4{0.f, 0.f, 0.f, 0.f};
    }
  const _Float16* Af = WFGl + (size_t)(32 * w + ml) * 256;
  const _Float16* Ag = Af + 128 * 256;
#pragma unroll
  for (int h = 0; h < 2; ++h) {
#pragma unroll
    for (int kk = 0; kk < 4; ++kk) {
      const int ko = kk * 32 + mq * 8;
      const int kw = h * 128 + ko;
      half8_t aF0 = *(const half8_t*)(Af + kw);
      half8_t aF1 = *(const half8_t*)(Af + 16 * 256 + kw);
      half8_t aG0 = *(const half8_t*)(Ag + kw);
      half8_t aG1 = *(const half8_t*)(Ag + 16 * 256 + kw);
#pragma unroll
      for (int nt = 0; nt < 8; ++nt) {
        half8_t bv = *(const half8_t*)((h ? brow1[nt] : brow0[nt]) + ko);
        accF[0][nt] = mfma16(aF0, bv, accF[0][nt]);
        accF[1][nt] = mfma16(aF1, bv, accF[1][nt]);
        accG[0][nt] = mfma16(aG0, bv, accG[0][nt]);
        accG[1][nt] = mfma16(aG1, bv, accG[1][nt]);
      }
    }
  }

  // ---- gate in registers ----
  half4_t og[2][8];
#pragma unroll
  for (int mt = 0; mt < 2; ++mt) {
    const int mb = 32 * w + mt * 16 + mq * 4;
    floatx4 bfv = *(const floatx4*)(bfl + mb);
    floatx4 bgv = *(const floatx4*)(bgl + mb);
#pragma unroll
    for (int nt = 0; nt < 8; ++nt) {
#pragma unroll
      for (int r = 0; r < 4; ++r) {
        float fv = fast_tanh(accF[mt][nt][r] + bfv[r]);
        float gv = fast_sigmoid(accG[mt][nt][r] + bgv[r]);
        og[mt][nt][r] = (_Float16)(fv * gv);
      }
    }
  }
  __syncthreads();  // b2: Xs0 tap reads done -> reuse as Os

  _Float16(*Os)[136] = Xs0;
#pragma unroll
  for (int mt = 0; mt < 2; ++mt) {
    const int mb = 32 * w + mt * 16 + mq * 4;
#pragma unroll
    for (int nt = 0; nt < 8; ++nt)
      *(half4_t*)&Os[nt * 16 + ml][mb] = og[mt][nt];
  }
  __syncthreads();  // b3

  // ---- GEMM2: x = WR(128x128) @ out ----
  floatx4 accX[2][8];
#pragma unroll
  for (int a = 0; a < 2; ++a)
#pragma unroll
    for (int cc = 0; cc < 8; ++cc) accX[a][cc] = floatx4{0.f, 0.f, 0.f, 0.f};
  const _Float16* Ar = WRl + (size_t)(32 * w + ml) * 128;
#pragma unroll
  for (int kk = 0; kk < 4; ++kk) {
    const int ko = kk * 32 + mq * 8;
    half8_t a0 = *(const half8_t*)(Ar + ko);
    half8_t a1 = *(const half8_t*)(Ar + 16 * 128 + ko);
#pragma unroll
    for (int nt = 0; nt < 8; ++nt) {
      half8_t bv = *(const half8_t*)&Os[nt * 16 + ml][ko];
      accX[0][nt] = mfma16(a0, bv, accX[0][nt]);
      accX[1][nt] = mfma16(a1, bv, accX[1][nt]);
    }
  }

  // ---- epilogue: R_new = x + br + R_old; publish tail FROM REGISTERS ----
  half4_t xo[2][8];
#pragma unroll
  for (int mt = 0; mt < 2; ++mt) {
    const int mb = 32 * w + mt * 16 + mq * 4;
    floatx4 brv = *(const floatx4*)(brl + mb);
#pragma unroll
    for (int nt = 0; nt < 8; ++nt) {
      const int n = nt * 16 + ml;
      half4_t rold = *(const half4_t*)&Rown[n][mb];
#pragma unroll
      for (int r = 0; r < 4; ++r)
        xo[mt][nt][r] = (_Float16)(accX[mt][nt][r] + brv[r] + (float)rold[r]);
    }
  }
  if (ext > 0) {  // plain stores; caller's vmcnt+barrier+flag orders them
#pragma unroll
    for (int mt = 0; mt < 2; ++mt) {
      const int mb = 32 * w + mt * 16 + mq * 4;
#pragma unroll
      for (int nt = 0; nt < 8; ++nt) {
        const int n = nt * 16 + ml;
        if (n >= TILE - ext)
          *(half4_t*)(pbout + (size_t)(u0 + n) * HIDC + mb) = xo[mt][nt];
      }
    }
  }
  __syncthreads();  // b4: all Rown (rold/tap) and Os reads done

#pragma unroll
  for (int mt = 0; mt < 2; ++mt) {
    const int mb = 32 * w + mt * 16 + mq * 4;
#pragma unroll
    for (int nt = 0; nt < 8; ++nt)
      *(half4_t*)&Rown[nt * 16 + ml][mb] = xo[mt][nt];
  }
  // no b5: caller's release barrier makes Rown visible
}

// ---------------- phase 21 (one 64-row half): head ----------------
__device__ __forceinline__ void head_half(
    const _Float16* __restrict__ R0g, const _Float16* __restrict__ W1h,
    const _Float16* __restrict__ W2h, const float* __restrict__ b1,
    const float* __restrict__ b2, float* __restrict__ outb, int u0t, int h,
    char* smem) {
  _Float16(*Rown)[136] = (_Float16(*)[136])smem;
  _Float16* Hs = (_Float16*)(smem + 34816);            // [64][136]
  _Float16* H1s = (_Float16*)(smem + 34816 + 17408);   // [64][136]
  const int u0 = u0t + 64 * h;
  const int tid = threadIdx.x;
  const int lane = tid & 63;
  const int w = tid >> 6;
  const int ml = lane & 15;
  const int mq = lane >> 4;

  // Hs = relu(Rfin(LDS) - R0(global, sc0))
  {
    const void* sp[4];
#pragma unroll
    for (int it = 0; it < 4; ++it) {
      int i = it * 256 + tid;
      sp[it] = R0g + (size_t)(u0 + (i >> 4)) * HIDC + (i & 15) * 8;
    }
    floatx4 z0, z1, z2, z3;
    cload4(sp[0], sp[1], sp[2], sp[3], z0, z1, z2, z3);
    floatx4 zz[4] = {z0, z1, z2, z3};
#pragma unroll
    for (int it = 0; it < 4; ++it) {
      int i = it * 256 + tid;
      int n = i >> 4; int cq = i & 15;
      half8_t a = *(const half8_t*)&Rown[64 * h + n][cq * 8];
      half8_t zv = *(half8_t*)&zz[it];
      half8_t hh;
#pragma unroll
      for (int tq = 0; tq < 8; ++tq) {
        float v = (float)a[tq] - (float)zv[tq];
        hh[tq] = (_Float16)(v > 0.f ? v : 0.f);
      }
      *(half8_t*)&Hs[n * 136 + cq * 8] = hh;
    }
  }
  __syncthreads();

  floatx4 accO[4][4];
#pragma unroll
  for (int a = 0; a < 4; ++a)
#pragma unroll
    for (int c = 0; c < 4; ++c) accO[a][c] = floatx4{0.f, 0.f, 0.f, 0.f};

  for (int p = 0; p < 4; ++p) {
    floatx4 acc1[2][4];
#pragma unroll
    for (int a = 0; a < 2; ++a)
#pragma unroll
      for (int c = 0; c < 4; ++c) acc1[a][c] = floatx4{0.f, 0.f, 0.f, 0.f};
    const _Float16* A1 = W1h + (size_t)(128 * p + 32 * w + ml) * 128;
#pragma unroll
    for (int kk = 0; kk < 4; ++kk) {
      const int ko = kk * 32 + mq * 8;
      half8_t av0 = *(const half8_t*)(A1 + ko);
      half8_t av1 = *(const half8_t*)(A1 + 16 * 128 + ko);
#pragma unroll
      for (int nt = 0; nt < 4; ++nt) {
        half8_t bv = *(const half8_t*)&Hs[(nt * 16 + ml) * 136 + ko];
        acc1[0][nt] = mfma16(av0, bv, acc1[0][nt]);
        acc1[1][nt] = mfma16(av1, bv, acc1[1][nt]);
      }
    }
    __syncthreads();
#pragma unroll
    for (int mt = 0; mt < 2; ++mt) {
      const int kc = 32 * w + mt * 16 + mq * 4;
      floatx4 bv = *(const floatx4*)(b1 + 128 * p + kc);
#pragma unroll
      for (int nt = 0; nt < 4; ++nt) {
        half4_t hh;
#pragma unroll
        for (int r = 0; r < 4; ++r) {
          float v = acc1[mt][nt][r] + bv[r];
          hh[r] = (_Float16)(v > 0.f ? v : 0.f);
        }
        *(half4_t*)&H1s[(nt * 16 + ml) * 136 + kc] = hh;
      }
    }
    __syncthreads();
    const _Float16* A2 = W2h + (size_t)(64 * w + ml) * 512 + p * 128;
#pragma unroll
    for (int kk = 0; kk < 4; ++kk) {
      const int ko = kk * 32 + mq * 8;
#pragma unroll
      for (int nt = 0; nt < 4; ++nt) {
        half8_t bv = *(const half8_t*)&H1s[(nt * 16 + ml) * 136 + ko];
#pragma unroll
        for (int mt = 0; mt < 4; ++mt) {
          half8_t av = *(const half8_t*)(A2 + (size_t)(mt * 16) * 512 + ko);
          accO[mt][nt] = mfma16(av, bv, accO[mt][nt]);
        }
      }
    }
    __syncthreads();
  }

  _Float16* Ot = (_Float16*)(smem + 34816);  // [64][264] over scratch
#pragma unroll
  for (int mt = 0; mt < 4; ++mt) {
    const int m = 64 * w + mt * 16 + mq * 4;
    floatx4 bv = *(const floatx4*)(b2 + m);
#pragma unroll
    for (int nt = 0; nt < 4; ++nt) {
      const int n = nt * 16 + ml;
      half4_t hh;
#pragma unroll
      for (int r = 0; r < 4; ++r) hh[r] = (_Float16)(accO[mt][nt][r] + bv[r]);
      *(half4_t*)&Ot[n * 264 + m] = hh;
    }
  }
  __syncthreads();
#pragma unroll
  for (int it = 0; it < 8; ++it) {
    int i = it * 256 + tid;
    int n = i >> 5;
    int g = i & 31;
    int u = u0 + n;
    if (u >= GOODC) {
      half8_t v = *(const half8_t*)&Ot[n * 264 + g * 8];
      float* dst = outb + (size_t)(u - GOODC) * 256 + g * 8;
      floatx4 v0, v1;
#pragma unroll
      for (int tq = 0; tq < 4; ++tq) { v0[tq] = (float)v[tq]; v1[tq] = (float)v[4 + tq]; }
      *(floatx4*)dst = v0;
      *(floatx4*)(dst + 4) = v1;
    }
  }
  __syncthreads();  // scratch safe before next half
}

// ---------------- persistent dataflow kernel ---------------------------------
__global__ __launch_bounds__(256, 2) void mega_kernel(
    const float* __restrict__ inp, const _Float16* __restrict__ WIh,
    const float* __restrict__ bi, const _Float16* __restrict__ WFG,
    const _Float16* __restrict__ WRh, const float* __restrict__ bf,
    const float* __restrict__ bg, const float* __restrict__ br,
    const _Float16* __restrict__ W1h, const _Float16* __restrict__ W2h,
    const float* __restrict__ b1, const float* __restrict__ b2,
    _Float16* __restrict__ R0g, _Float16* __restrict__ Ah,
    _Float16* __restrict__ Bh, _Float16* __restrict__ Ch,
    float* __restrict__ out, int nslots) {
  __shared__ __align__(16) char smem[69632];
  __shared__ int s_j, s_bb, s_light;
  const int tid = threadIdx.x;

  // ---- startup: XCD self-assignment + bounded rendezvous ----
  if (tid == 0) {
    unsigned xcd;
    asm volatile("s_getreg_b32 %0, hwreg(HW_REG_XCC_ID)" : "=s"(xcd));
    xcd &= 7;
    int slot = __hip_atomic_fetch_add(&g_qhead[xcd], 1, __ATOMIC_RELAXED,
                                      __HIP_MEMORY_SCOPE_AGENT);
    __hip_atomic_fetch_add(&g_arrive, 1, __ATOMIC_RELEASE,
                           __HIP_MEMORY_SCOPE_AGENT);
    int ok = 1, it = 0;
    while (__hip_atomic_load(&g_arrive, __ATOMIC_ACQUIRE,
                             __HIP_MEMORY_SCOPE_AGENT) < NBLK) {
      if (++it > RDV_CAP) {
        ok = 0;
        __hip_atomic_store(&g_broken, 1, __ATOMIC_RELAXED,
                           __HIP_MEMORY_SCOPE_AGENT);
        break;
      }
      __builtin_amdgcn_s_sleep(8);
    }
    int light = ok;
    if (ok) {
#pragma unroll
      for (int x = 0; x < 8; ++x)
        light &= (__hip_atomic_load(&g_qhead[x], __ATOMIC_RELAXED,
                                    __HIP_MEMORY_SCOPE_AGENT) == NBLK / 8);
    }
    if (light) { s_bb = (int)xcd; s_j = slot; }
    else       { s_bb = blockIdx.x >> 6; s_j = blockIdx.x & 63; }
    s_light = light;
  }
  __syncthreads();
  const int j = s_j;
  const int bb = s_bb;
  const int light = s_light;
  const int u0 = j * TILE;

  _Float16* R0b = R0g + (size_t)bb * TT * HIDC;
  _Float16* sl[3] = {Ah + (size_t)bb * TT * HIDC, Bh + (size_t)bb * TT * HIDC,
                     Ch + (size_t)bb * TT * HIDC};
  const float* ib = inp + (size_t)bb * 256 * TT;
  float* outb = out + (size_t)bb * TGT * 256;
  int* myflag = &g_progress[bb * NTB + j];

#pragma unroll 1
  for (int q = 0; q < 22; ++q) {
    // ---- gate: 1 RAW producer + <=1 WAR reader (slot-rotation aware) ----
    if (q >= 1 && q <= 20) {
      const int dq = 1 << ((q - 1) % 10);
      const int jraw = j - ((dq + TILE - 1) >> 7);
      int jwar = -1, warq = 0;
      if (q > nslots) {
        const int p = q - nslots + 1;        // reader phase of reused slot
        const int dp = 1 << ((p - 1) % 10);
        int cand = j + ((dp + TILE - 1) >> 7);
        if (cand <= NTB - 1) { jwar = cand; warq = q - nslots + 2; }
      }
      if (tid == 0 && jraw >= 0) spin_tile(bb * NTB + jraw, q);
      if (tid == 1 && jwar >= 0) spin_tile(bb * NTB + jwar, warq);
      __syncthreads();
      if (!light) __builtin_amdgcn_fence(__ATOMIC_ACQUIRE, "agent");
    }

    // ---- phase body ----
    if (q == 0) {
      input_half(ib, WIh, bi, R0b, u0, 0, smem);
      input_half(ib, WIh, bi, R0b, u0, 1, smem);
    } else if (q <= 20) {
      const int l = q - 1;
      const int d = 1 << (l % 10);
      const _Float16* pbin = (q == 1) ? R0b : sl[(q - 2) % nslots];
      _Float16* pbout = sl[(q - 1) % nslots];
      int ext = 0;
      if (q <= 19) {
        ext = 1 << (q % 10);
        if (ext > TILE) ext = TILE;
      }
      phase_layer(pbin, pbout, WFG + (size_t)l * 65536,
                  WRh + (size_t)l * 16384, bf + l * 128, bg + l * 128,
                  br + l * 128, d, u0, ext, smem);
    } else {
      if (u0 + 127 >= GOODC) {
        if (u0 + 63 >= GOODC)
          head_half(R0b, W1h, W2h, b1, b2, outb, u0, 0, smem);
        head_half(R0b, W1h, W2h, b1, b2, outb, u0, 1, smem);
      }
    }

    // ---- release: vmcnt drain -> barrier (also Rown visibility) -> flag ----
    if (q <= 20) {
      if (light) {
        asm volatile("s_waitcnt vmcnt(0)" ::: "memory");  // data ack'd at L2
      } else {
        __builtin_amdgcn_fence(__ATOMIC_RELEASE, "agent");
      }
      __syncthreads();
      if (q <= 19 && tid == 0)  // nothing spins >= 21
        __hip_atomic_store(myflag, q + 1, __ATOMIC_RELAXED,
                           __HIP_MEMORY_SCOPE_AGENT);
    }
  }
}

extern "C" void kernel_launch(void* const* d_in, const int* in_sizes, int n_in,
                              void* d_out, int out_size, void* d_ws, size_t ws_size,
                              hipStream_t stream) {
  const float* inputs = (const float*)d_in[0];
  const float* Wi = (const float*)d_in[1];
  const float* bi = (const float*)d_in[2];
  const float* Wf = (const float*)d_in[3];
  const float* bf = (const float*)d_in[4];
  const float* Wg = (const float*)d_in[5];
  const float* bg = (const float*)d_in[6];
  const float* Wr = (const float*)d_in[7];
  const float* br = (const float*)d_in[8];
  const float* W1 = (const float*)d_in[9];
  const float* b1 = (const float*)d_in[10];
  const float* W2 = (const float*)d_in[11];
  const float* b2 = (const float*)d_in[12];
  float* out = (float*)d_out;

  // workspace: R0g + 2-or-3 rotation slabs (host-picked from ws_size) + weights
  const size_t SLAB = 16777216;
  int nslots = (ws_size >= 4 * SLAB + 4194304) ? 3 : 2;
  char* ws = (char*)d_ws;
  _Float16* R0g = (_Float16*)(ws + 0);
  _Float16* Ah  = (_Float16*)(ws + SLAB);
  _Float16* Bh  = (_Float16*)(ws + 2 * SLAB);
  _Float16* Ch  = (_Float16*)(ws + (nslots == 3 ? 3 * SLAB : 2 * SLAB));
  char* wb = ws + (size_t)(nslots == 3 ? 4 : 3) * SLAB;
  _Float16* WFG = (_Float16*)(wb);
  _Float16* WRh = (_Float16*)(wb + 2621440);
  _Float16* WIh = (_Float16*)(wb + 3276800);
  _Float16* W1h = (_Float16*)(wb + 3342336);
  _Float16* W2h = (_Float16*)(wb + 3473408);

  prep_kernel<<<dim3(512), dim3(256), 0, stream>>>(Wi, Wf, Wg, Wr, W1, W2,
                                                   WIh, WFG, WRh, W1h, W2h);
  mega_kernel<<<dim3(NBLK), dim3(256), 0, stream>>>(
      inputs, WIh, bi, WFG, WRh, bf, bg, br, W1h, W2h, b1, b2,
      R0g, Ah, Bh, Ch, out, nslots);
}